// Round 1
// baseline (199.389 us; speedup 1.0000x reference)
//
#include <hip/hip_runtime.h>
#include <math.h>

// Problem constants (match reference)
constexpr int B = 1024;
constexpr int S = 50;
constexpr int H = 64;
constexpr int V = 40000;

// One block per batch row. 256 threads = 4 waves.
//  - zero own output row (harness poisons d_out to 0xAA every call)
//  - stage all_memory[b] + Ur into LDS, Ur row -> registers per lane
//  - lane k computes l[b,k]; waves split s; shfl butterfly for the k-sum
//  - wave 0: softmax over S=50; then 50 atomicAdds (duplicates accumulate)
__global__ __launch_bounds__(256) void rrd_fused_kernel(
    const float* __restrict__ am,    // [B,S,H]
    const float* __restrict__ lm,    // [B,H]
    const int*   __restrict__ items, // [B,S] int32
    const float* __restrict__ Wr,    // [H,H]
    const float* __restrict__ Ur,    // [H,H]
    const float* __restrict__ Vw,    // [H]
    const float* __restrict__ Vb,    // [1]
    float* __restrict__ out)         // [B,V]
{
    const int b    = blockIdx.x;
    const int tid  = threadIdx.x;
    const int lane = tid & 63;
    const int wave = tid >> 6;

    __shared__ float s_am[S * H];         // 12.8 KB, broadcast reads later
    __shared__ float s_Ur[H * (H + 1)];   // +1 pad: (k,k+32) 2-way alias = free
    __shared__ float s_l[H];
    __shared__ float s_sc[S];
    __shared__ float s_probs[S];

    // ---- 1) zero this block's output row (write-BW bound part) ----
    float4* row4 = reinterpret_cast<float4*>(out + (size_t)b * V);
    const float4 z4 = make_float4(0.f, 0.f, 0.f, 0.f);
    #pragma unroll 4
    for (int i = tid; i < V / 4; i += 256) row4[i] = z4;   // V%4==0, 16B aligned

    // ---- 2) stage inputs ----
    for (int i = tid; i < S * H; i += 256) s_am[i] = am[(size_t)b * S * H + i];
    for (int i = tid; i < H * H; i += 256)
        s_Ur[(i >> 6) * (H + 1) + (i & 63)] = Ur[i];

    // l[b,k] = <last_memory[b,:], Wr[k,:]>  (Wr is 16KB, L2-hot)
    if (tid < H) {
        float acc = 0.f;
        const float* wr = Wr + tid * H;
        const float* l0 = lm + (size_t)b * H;
        #pragma unroll
        for (int h = 0; h < H; ++h) acc = fmaf(l0[h], wr[h], acc);
        s_l[tid] = acc;
    }
    __syncthreads();

    // Ur row of this lane into registers (one-time, 2-way-free LDS reads)
    float ur[H];
    #pragma unroll
    for (int h = 0; h < H; ++h) ur[h] = s_Ur[lane * (H + 1) + h];
    const float vw = Vw[lane];
    const float lk = s_l[lane];

    // ---- 3) scores: wave w handles s = w, w+4, ... ----
    for (int s = wave; s < S; s += 4) {
        const float4* a4 = reinterpret_cast<const float4*>(s_am + s * H);
        float acc = lk;
        #pragma unroll
        for (int i = 0; i < H / 4; ++i) {   // 16 broadcast ds_read_b128
            float4 v = a4[i];
            acc = fmaf(v.x, ur[4 * i + 0], acc);
            acc = fmaf(v.y, ur[4 * i + 1], acc);
            acc = fmaf(v.z, ur[4 * i + 2], acc);
            acc = fmaf(v.w, ur[4 * i + 3], acc);
        }
        float t = tanhf(acc) * vw;
        #pragma unroll
        for (int off = 32; off; off >>= 1) t += __shfl_xor(t, off, 64);
        if (lane == 0) s_sc[s] = t + Vb[0];
    }
    __syncthreads();

    // ---- 4) softmax over S (wave 0) ----
    if (wave == 0) {
        float x = (lane < S) ? s_sc[lane] : -INFINITY;
        float m = x;
        #pragma unroll
        for (int off = 32; off; off >>= 1) m = fmaxf(m, __shfl_xor(m, off, 64));
        float e = (lane < S) ? expf(x - m) : 0.f;
        float sum = e;
        #pragma unroll
        for (int off = 32; off; off >>= 1) sum += __shfl_xor(sum, off, 64);
        if (lane < S) s_probs[lane] = e / sum;
    }
    __syncthreads();  // also drains the row-zero stores (vmcnt(0) before barrier)

    // ---- 5) scatter: duplicates within a sequence accumulate ----
    if (tid < S) {
        const int it = items[b * S + tid];
        atomicAdd(out + (size_t)b * V + it, s_probs[tid]);
    }
}

extern "C" void kernel_launch(void* const* d_in, const int* in_sizes, int n_in,
                              void* d_out, int out_size, void* d_ws, size_t ws_size,
                              hipStream_t stream) {
    const float* am    = (const float*)d_in[0];  // all_memory [B,S,H]
    const float* lm    = (const float*)d_in[1];  // last_memory [B,H]
    const int*   items = (const int*)  d_in[2];  // seq_item [B,S]
    const float* Wr    = (const float*)d_in[3];  // [H,H]
    const float* Ur    = (const float*)d_in[4];  // [H,H]
    const float* Vw    = (const float*)d_in[5];  // [H]
    const float* Vb    = (const float*)d_in[6];  // scalar
    float* out = (float*)d_out;                  // [B,V] fp32

    rrd_fused_kernel<<<dim3(B), dim3(256), 0, stream>>>(
        am, lm, items, Wr, Ur, Vw, Vb, out);
}